// Round 1
// 148.616 us; speedup vs baseline: 1.0052x; 1.0052x over previous
//
#include <hip/hip_runtime.h>
#include <hip/hip_bf16.h>

typedef __attribute__((ext_vector_type(8))) short v8s;            // 8 x bf16 (4 VGPRs) MFMA A/B
typedef __attribute__((ext_vector_type(8))) unsigned short u16x8;
typedef __attribute__((ext_vector_type(4))) float v4f;            // 16x16 MFMA C/D
typedef __attribute__((ext_vector_type(16))) float f32x16;        // 32x32 MFMA C/D

#define MFMA16(a, b, c) __builtin_amdgcn_mfma_f32_16x16x32_bf16((a), (b), (c), 0, 0, 0)
#define MFMA32(a, b, c) __builtin_amdgcn_mfma_f32_32x32x16_bf16((a), (b), (c), 0, 0, 0)

// async global->LDS, 16B per lane; LDS dest = wave-uniform base + lane*16
#define GLL16(g, l)                                                        \
  __builtin_amdgcn_global_load_lds(                                        \
      (const __attribute__((address_space(1))) unsigned int*)(g),          \
      (__attribute__((address_space(3))) unsigned int*)(l), 16, 0, 0)

// native v_exp_f32 (libm exp2f is a multi-op software expansion)
#if __has_builtin(__builtin_amdgcn_exp2f)
__device__ __forceinline__ float exp2n(float x) { return __builtin_amdgcn_exp2f(x); }
#else
__device__ __forceinline__ float exp2n(float x) {
  float r; asm("v_exp_f32 %0, %1" : "=v"(r) : "v"(x)); return r;
}
#endif

__device__ __forceinline__ unsigned short f2bf(float f) {
  union { float f; unsigned u; } v; v.f = f;
  unsigned r = v.u + 0x7fffu + ((v.u >> 16) & 1u);   // RNE
  return (unsigned short)(r >> 16);
}

// RNE pack of two f32 -> bf16x2 (lo in low half) in one VOP3
__device__ __forceinline__ unsigned cvtpk(float lo, float hi) {
  unsigned r;
  asm("v_cvt_pk_bf16_f32 %0, %1, %2" : "=v"(r) : "v"(lo), "v"(hi));
  return r;
}
// gfx950: swap high 32 lanes of a with low 32 lanes of b (both modified)
__device__ __forceinline__ void pl32swap(unsigned& a, unsigned& b) {
  asm("v_permlane32_swap_b32 %0, %1" : "+v"(a), "+v"(b));
}

// ---------------- fused: weight fp32->bf16 convert  +  GroupNorm stats ----------------
__global__ __launch_bounds__(256) void cvt_gn_kernel(const float* __restrict__ in0,
                                                     unsigned short* __restrict__ out0,
                                                     const float* __restrict__ in1,
                                                     unsigned short* __restrict__ out1,
                                                     int n0, int n1,
                                                     const float* __restrict__ x,
                                                     float2* __restrict__ stats) {
  if (blockIdx.x < 1024) {
    int i = blockIdx.x * 256 + threadIdx.x;
    const float* in; unsigned short* out;
    if (i < n0) { in = in0; out = out0; }
    else        { i -= n0; if (i >= n1) return; in = in1; out = out1; }
    float4 v = ((const float4*)in)[i];
    ushort4 o;
    o.x = f2bf(v.x); o.y = f2bf(v.y); o.z = f2bf(v.z); o.w = f2bf(v.w);
    ((ushort4*)out)[i] = o;
    return;
  }
  const int bg = blockIdx.x - 1024;            // 0..255
  const float4* xp4 = (const float4*)(x + (size_t)bg * 16 * 1024);
  float s = 0.f, ss = 0.f;
  for (int i = threadIdx.x; i < 4096; i += 256) {
    float4 v = xp4[i];
    s  += (v.x + v.y) + (v.z + v.w);
    ss += (v.x * v.x + v.y * v.y) + (v.z * v.z + v.w * v.w);
  }
  #pragma unroll
  for (int d = 1; d < 64; d <<= 1) { s += __shfl_xor(s, d); ss += __shfl_xor(ss, d); }
  __shared__ float red[2][4];
  const int w = threadIdx.x >> 6;
  if ((threadIdx.x & 63) == 0) { red[0][w] = s; red[1][w] = ss; }
  __syncthreads();
  if (threadIdx.x == 0) {
    s  = red[0][0] + red[0][1] + red[0][2] + red[0][3];
    ss = red[1][0] + red[1][1] + red[1][2] + red[1][3];
    const float mu  = s * (1.f / 16384.f);
    const float var = ss * (1.f / 16384.f) - mu * mu;
    stats[bg] = make_float2(mu, rsqrtf(var + 1e-5f));
  }
}

// ---------------- GroupNorm normalize + transpose: x[b][c][l] -> xnT[b][l][c] bf16 ----
__global__ __launch_bounds__(256) void gnt_kernel(const float* __restrict__ x,
                                                  const float2* __restrict__ stats,
                                                  const float* __restrict__ gsc,
                                                  const float* __restrict__ gbi,
                                                  unsigned short* __restrict__ xnT) {
  const int b = blockIdx.z, l0 = blockIdx.x * 64, c0 = blockIdx.y * 64;
  const float* sp = x + (size_t)b * 512 * 1024;
  unsigned short* dp = xnT + (size_t)b * 1024 * 512;
  __shared__ unsigned T[64][65];
  const int tid = threadIdx.x;
  const int rr = tid >> 3, c8 = (tid & 7) * 8;
  #pragma unroll
  for (int sw = 0; sw < 2; ++sw) {
    const int c = c0 + sw * 32 + rr;
    const float2 st = stats[b * 32 + (c >> 4)];
    const float sc = gsc[c] * st.y;
    const float bi = gbi[c] - st.x * sc;
    const float4* px = (const float4*)(sp + (size_t)c * 1024 + l0 + c8);
    float4 v0 = px[0], v1 = px[1];
    T[sw * 32 + rr][c8 + 0] = f2bf(v0.x * sc + bi);
    T[sw * 32 + rr][c8 + 1] = f2bf(v0.y * sc + bi);
    T[sw * 32 + rr][c8 + 2] = f2bf(v0.z * sc + bi);
    T[sw * 32 + rr][c8 + 3] = f2bf(v0.w * sc + bi);
    T[sw * 32 + rr][c8 + 4] = f2bf(v1.x * sc + bi);
    T[sw * 32 + rr][c8 + 5] = f2bf(v1.y * sc + bi);
    T[sw * 32 + rr][c8 + 6] = f2bf(v1.z * sc + bi);
    T[sw * 32 + rr][c8 + 7] = f2bf(v1.w * sc + bi);
  }
  __syncthreads();
  #pragma unroll
  for (int sw = 0; sw < 2; ++sw) {
    const int ll = sw * 32 + rr;
    u16x8 o;
    #pragma unroll
    for (int j = 0; j < 8; ++j) o[j] = (unsigned short)T[c8 + j][ll];
    *(u16x8*)(dp + (size_t)(l0 + ll) * 512 + c0 + c8) = o;
  }
}

// ---------------- 128xNT MFMA GEMM, BK=64, xor-swizzled 128B LDS rows ----------------
template <bool QKV, int NT>
__global__ __launch_bounds__(256) void gemm_kernel(
    const unsigned short* __restrict__ A,
    const unsigned short* __restrict__ BT,
    const float* __restrict__ bias,
    const float* __restrict__ xres,
    float* __restrict__ outf,
    unsigned short* __restrict__ qT,
    unsigned short* __restrict__ kT,
    unsigned short* __restrict__ vO) {
  constexpr int K = 512;
  constexpr int NFR = NT / 32;              // n-frags per wave
  constexpr int NJOB = 16 + NT / 8;         // staging jobs (A:16, B:NT/8)
  const int n0 = blockIdx.x * NT, m0 = blockIdx.y * 128, b = blockIdx.z;
  const unsigned short* Bp = BT + (size_t)b * 1024 * K;

  __shared__ __align__(16) unsigned short As[128][64];
  __shared__ __align__(16) unsigned short Bs[NT][64];

  const int tid = threadIdx.x, lane = tid & 63, w = tid >> 6;
  const int quad = lane >> 4, l15 = lane & 15;
  const int wm = (w >> 1) * 64, wn = (w & 1) * (NT / 2);
  const int srow = lane >> 3;
  const int scol = ((lane & 7) ^ srow) * 8;
  const int ck0 = ((quad ^ (l15 & 7)) * 8);
  const int ck1 = ck0 ^ 32;
  const unsigned short* Asf = &As[0][0];
  const unsigned short* Bsf = &Bs[0][0];

  v4f acc[4][NFR];
  #pragma unroll
  for (int i = 0; i < 4; ++i)
    #pragma unroll
    for (int j = 0; j < NFR; ++j) acc[i][j] = (v4f){0.f, 0.f, 0.f, 0.f};

  for (int kk = 0; kk < K; kk += 64) {
    __syncthreads();
    #pragma unroll
    for (int jj = 0; jj < NJOB / 4; ++jj) {
      const int job = w * (NJOB / 4) + jj;
      if (job < 16) {
        GLL16(A + (size_t)(m0 + job * 8 + srow) * K + kk + scol, &As[job * 8][0]);
      } else {
        const int j2 = job - 16;
        GLL16(Bp + (size_t)(n0 + j2 * 8 + srow) * K + kk + scol, &Bs[j2 * 8][0]);
      }
    }
    __syncthreads();
    #pragma unroll
    for (int h = 0; h < 2; ++h) {
      const int ck = h ? ck1 : ck0;
      v8s af[4], bf[NFR];
      #pragma unroll
      for (int mt = 0; mt < 4; ++mt) af[mt] = *(const v8s*)(Asf + (wm + mt * 16 + l15) * 64 + ck);
      #pragma unroll
      for (int nt = 0; nt < NFR; ++nt) bf[nt] = *(const v8s*)(Bsf + (wn + nt * 16 + l15) * 64 + ck);
      #pragma unroll
      for (int mt = 0; mt < 4; ++mt)
        #pragma unroll
        for (int nt = 0; nt < NFR; ++nt)
          acc[mt][nt] = MFMA16(af[mt], bf[nt], acc[mt][nt]);
    }
  }

  if (QKV) {
    const int bh8 = b * 8;
    const float cs = 0.18033688011112042f;   // 0.125 * log2(e), folded into q
    #pragma unroll
    for (int mt = 0; mt < 4; ++mt) {
      const int m4 = m0 + wm + mt * 16 + quad * 4;
      const int h = m4 / 192;
      const int rr = m4 - h * 192;
      const int part = rr >> 6;                          // 0=q 1=k 2=v
      const int ch = rr & 63;
      const float b0 = bias[m4], b1 = bias[m4 + 1], b2 = bias[m4 + 2], b3 = bias[m4 + 3];
      #pragma unroll
      for (int nt = 0; nt < NFR; ++nt) {
        const int n = n0 + wn + nt * 16 + l15;
        v4f a = acc[mt][nt];
        const float v0 = a[0] + b0, v1 = a[1] + b1, v2 = a[2] + b2, v3 = a[3] + b3;
        if (part == 0) {
          ushort4 st4;
          st4.x = f2bf(v0 * cs); st4.y = f2bf(v1 * cs);
          st4.z = f2bf(v2 * cs); st4.w = f2bf(v3 * cs);
          *(ushort4*)(qT + ((size_t)(bh8 + h) * 1024 + n) * 64 + ch) = st4;
        } else if (part == 1) {
          ushort4 st4;
          st4.x = f2bf(v0); st4.y = f2bf(v1); st4.z = f2bf(v2); st4.w = f2bf(v3);
          *(ushort4*)(kT + ((size_t)(bh8 + h) * 1024 + n) * 64 + ch) = st4;
        } else {
          unsigned short* dp = vO + ((size_t)(bh8 + h) * 64 + ch) * 1024 + n;
          dp[0] = f2bf(v0); dp[1024] = f2bf(v1); dp[2048] = f2bf(v2); dp[3072] = f2bf(v3);
        }
      }
    }
  } else {
    #pragma unroll
    for (int mt = 0; mt < 4; ++mt) {
      const int m4 = m0 + wm + mt * 16 + quad * 4;
      const float b0 = bias[m4], b1 = bias[m4 + 1], b2 = bias[m4 + 2], b3 = bias[m4 + 3];
      #pragma unroll
      for (int nt = 0; nt < NFR; ++nt) {
        const int n = n0 + wn + nt * 16 + l15;
        const size_t i0 = ((size_t)b * 512 + m4) * 1024 + n;
        outf[i0]        = xres[i0]        + acc[mt][nt][0] + b0;
        outf[i0 + 1024] = xres[i0 + 1024] + acc[mt][nt][1] + b1;
        outf[i0 + 2048] = xres[i0 + 2048] + acc[mt][nt][2] + b2;
        outf[i0 + 3072] = xres[i0 + 3072] + acc[mt][nt][3] + b3;
      }
    }
  }
}

// ---------------- Flash attention: 256q/block, 64 q/wave, 128-s K/V tiles ------------
// qT/kT: [bh][1024][64] bf16 (q pre-scaled by 0.125*log2e); v: [bh][64][1024] bf16.
// grid = (bh, t): ID = bh + 64*t -> a head's t-blocks share an XCD (L2 K/V reuse).
// NEW (this round): all MFMA moved to 32x32x16 bf16 (2495 TF ubench vs 2075 for 16x16,
// and it kills the half-rate 16x16x16 PV path): per wave 512 MFMA instead of 1536.
// S^T C-layout (col=lane&31, row=(reg&3)+8*(reg>>2)+4*(lane>>5)) is converted to the
// PV 32x32x16 A-fragment (A[m=lane&31][k=8*(lane>>5)+j]) with 8 v_cvt_pk_bf16_f32 +
// 4 v_permlane32_swap_b32 per 32x32 P-tile:
//   C0=pk(p0,p1) C1=pk(p2,p3) C2=pk(p4,p5) C3=pk(p6,p7)      (s-pairs per C-layout)
//   swap(C0,C2): C0 -> word0 (lo:s01, hi:s89), C2 -> word2 (lo:s45, hi:s12_13)
//   swap(C1,C3): C1 -> word1,                  C3 -> word3            (checked per-lane)
__global__ __launch_bounds__(256) void attn_kernel(const unsigned short* __restrict__ qT,
                                                   const unsigned short* __restrict__ kT,
                                                   const unsigned short* __restrict__ vv,
                                                   unsigned short* __restrict__ aT) {
  const int bh = blockIdx.x;
  const int t0 = blockIdx.y * 256;
  const unsigned short* qb = qT + (size_t)bh * 1024 * 64;
  const unsigned short* kb = kT + (size_t)bh * 1024 * 64;
  const unsigned short* vb = vv + (size_t)bh * 64 * 1024;

  __shared__ __align__(16) unsigned short Ks[2][128][64];    // 32KB [buf][s][k]
  __shared__ __align__(16) unsigned short Vs[2][2][64][64];  // 32KB [buf][s-half][c][s64]

  const int tid = threadIdx.x, w = tid >> 6, lane = tid & 63;
  const int l31 = lane & 31, h = lane >> 5;
  const int srow = lane >> 3;
  const int scol = ((lane & 7) ^ srow) * 8;

  // ---- stage Q (256 rows) through Ks[0..1] (exactly 256 rows), read B-frags ----
  #pragma unroll
  for (int jj = 0; jj < 8; ++jj) {
    const int seg = w * 8 + jj;              // 32 segs of 8 rows
    GLL16(qb + (size_t)(t0 + seg * 8 + srow) * 64 + scol, &Ks[0][0][0] + seg * 8 * 64);
  }
  __syncthreads();
  // Q B-frag for QK^T: B[k=ch][n=t]; lane: n = l31, k-chunk = kb2*16 + h*8
  v8s qf[2][4];
  #pragma unroll
  for (int tb = 0; tb < 2; ++tb) {
    const int row = w * 64 + tb * 32 + l31;  // row&7 == l31&7 (swizzle-consistent)
    const unsigned short* qr = &Ks[0][0][0] + row * 64;
    const int rx = row & 7;
    #pragma unroll
    for (int kb2 = 0; kb2 < 4; ++kb2)
      qf[tb][kb2] = *(const v8s*)(qr + ((kb2 * 2 + h) ^ rx) * 8);
  }
  __syncthreads();   // all waves done reading Q before Ks is overwritten

  // ---- stage K/V tile 0 (128 s): 32 jobs of 8 rows, 8 per wave ----
  #pragma unroll
  for (int jj = 0; jj < 8; ++jj) {
    const int j = w * 8 + jj;
    if (j < 16) {
      GLL16(kb + (size_t)(j * 8 + srow) * 64 + scol, &Ks[0][j * 8][0]);
    } else {
      const int j2 = j - 16, hf = j2 >> 3, cg = (j2 & 7) * 8;
      GLL16(vb + (size_t)(cg + srow) * 1024 + hf * 64 + scol, &Vs[0][hf][cg][0]);
    }
  }

  f32x16 o[2][2];
  #pragma unroll
  for (int tb = 0; tb < 2; ++tb)
    #pragma unroll
    for (int cb = 0; cb < 2; ++cb)
      #pragma unroll
      for (int r = 0; r < 16; ++r) o[tb][cb][r] = 0.f;
  float lsum[2] = {0.f, 0.f};

  for (int it = 0; it < 8; ++it) {
    __syncthreads();          // tile(it) resident (drains prefetch issued last iter)
    if (it + 1 < 8) {         // prefetch tile it+1 before compute of tile it
      const int s1 = (it + 1) * 128, bp1 = (it + 1) & 1;
      #pragma unroll
      for (int jj = 0; jj < 8; ++jj) {
        const int j = w * 8 + jj;
        if (j < 16) {
          GLL16(kb + (size_t)(s1 + j * 8 + srow) * 64 + scol, &Ks[bp1][j * 8][0]);
        } else {
          const int j2 = j - 16, hf = j2 >> 3, cg = (j2 & 7) * 8;
          GLL16(vb + (size_t)(cg + srow) * 1024 + s1 + hf * 64 + scol,
                &Vs[bp1][hf][cg][0]);
        }
      }
    }
    const int buf = it & 1;

    #pragma unroll
    for (int hf = 0; hf < 2; ++hf) {
      const unsigned short* Kb = &Ks[buf][hf * 64][0];
      const unsigned short* Vb = &Vs[buf][hf][0][0];

      // hoist K (A-frag: m = s = l31 + 32*sb) and V (B-frag: n = c = l31 + 32*cb)
      v8s kf[2][4], vf[2][4];
      #pragma unroll
      for (int sb = 0; sb < 2; ++sb) {
        const int row = sb * 32 + l31, rx = row & 7;
        const unsigned short* kr = Kb + row * 64;
        #pragma unroll
        for (int kb2 = 0; kb2 < 4; ++kb2)
          kf[sb][kb2] = *(const v8s*)(kr + ((kb2 * 2 + h) ^ rx) * 8);
      }
      #pragma unroll
      for (int cb = 0; cb < 2; ++cb) {
        const int row = cb * 32 + l31, rx = row & 7;
        const unsigned short* vr = Vb + row * 64;
        #pragma unroll
        for (int i = 0; i < 4; ++i)      // i = 16-wide s-block within this 64-s half
          vf[cb][i] = *(const v8s*)(vr + ((i * 2 + h) ^ rx) * 8);
      }

      #pragma unroll
      for (int tb = 0; tb < 2; ++tb) {
        #pragma unroll
        for (int sb = 0; sb < 2; ++sb) {
          // S^T(32s x 32t) = K * Q^T over 64 ch (4 chained k-blocks)
          f32x16 sa = {0.f,0.f,0.f,0.f,0.f,0.f,0.f,0.f,0.f,0.f,0.f,0.f,0.f,0.f,0.f,0.f};
          #pragma unroll
          for (int kb2 = 0; kb2 < 4; ++kb2)
            sa = MFMA32(kf[sb][kb2], qf[tb][kb2], sa);
          // softmax without max subtraction (q pre-scaled by log2e)
          float p[16]; float rsum = 0.f;
          #pragma unroll
          for (int r = 0; r < 16; ++r) { p[r] = exp2n(sa[r]); rsum += p[r]; }
          lsum[tb] += rsum;
          // pack P -> two 32x32x16 A-fragments (s 0..15 and 16..31)
          unsigned c0 = cvtpk(p[0], p[1]),  c1 = cvtpk(p[2], p[3]);
          unsigned c2 = cvtpk(p[4], p[5]),  c3 = cvtpk(p[6], p[7]);
          pl32swap(c0, c2); pl32swap(c1, c3);
          unsigned c4 = cvtpk(p[8], p[9]),  c5 = cvtpk(p[10], p[11]);
          unsigned c6 = cvtpk(p[12], p[13]), c7 = cvtpk(p[14], p[15]);
          pl32swap(c4, c6); pl32swap(c5, c7);
          union { v8s v; unsigned u[4]; } pa0, pa1;
          pa0.u[0] = c0; pa0.u[1] = c1; pa0.u[2] = c2; pa0.u[3] = c3;
          pa1.u[0] = c4; pa1.u[1] = c5; pa1.u[2] = c6; pa1.u[3] = c7;
          // O(32t x 64c) += P * V
          #pragma unroll
          for (int cb = 0; cb < 2; ++cb) {
            o[tb][cb] = MFMA32(pa0.v, vf[cb][sb * 2 + 0], o[tb][cb]);
            o[tb][cb] = MFMA32(pa1.v, vf[cb][sb * 2 + 1], o[tb][cb]);
          }
        }
      }
    }
  }

  // final l reduce across halves; write aT[b][t][hd*64+c] = O[t][c] / l(t)
  const int b = bh >> 3, hd = bh & 7;
  #pragma unroll
  for (int tb = 0; tb < 2; ++tb) {
    lsum[tb] += __shfl_xor(lsum[tb], 32);
    #pragma unroll
    for (int r = 0; r < 16; ++r) {
      const int trow = (r & 3) + 8 * (r >> 2) + 4 * h;
      const float inv = 1.0f / __shfl(lsum[tb], trow);
      const int t = t0 + w * 64 + tb * 32 + trow;
      unsigned short* dst = aT + ((size_t)b * 1024 + t) * 512 + hd * 64;
      dst[l31]      = f2bf(o[tb][0][r] * inv);
      dst[32 + l31] = f2bf(o[tb][1][r] * inv);
    }
  }
}

extern "C" void kernel_launch(void* const* d_in, const int* in_sizes, int n_in,
                              void* d_out, int out_size, void* d_ws, size_t ws_size,
                              hipStream_t stream) {
  const float* x    = (const float*)d_in[0];
  const float* gsc  = (const float*)d_in[1];
  const float* gbi  = (const float*)d_in[2];
  const float* qkvw = (const float*)d_in[3];
  const float* qkvb = (const float*)d_in[4];
  const float* pjw  = (const float*)d_in[5];
  const float* pjb  = (const float*)d_in[6];
  float* out = (float*)d_out;

  unsigned short* ws  = (unsigned short*)d_ws;
  unsigned short* qw  = ws;                   //  786432  qkv weights bf16
  unsigned short* pw  = qw + 786432;          //  262144  proj weights bf16
  float2* stats = (float2*)(pw + 262144);     //  256 float2 = 1024 shorts
  unsigned short* xnT = pw + 262144 + 1024;   // 4194304  [b][l][c]
  unsigned short* qT  = xnT + 4194304;        // 4194304  [bh][l][64]
  unsigned short* kT  = qT + 4194304;         // 4194304  [bh][l][64]
  unsigned short* vv  = kT + 4194304;         // 4194304  [bh][64][l]
  unsigned short* aT  = vv + 4194304;         // 4194304  [b][l][c]
  // total ~44.04 MB

  cvt_gn_kernel<<<dim3(1280), dim3(256), 0, stream>>>(qkvw, qw, pjw, pw, 196608, 65536,
                                                      x, stats);
  gnt_kernel<<<dim3(16, 8, 8), dim3(256), 0, stream>>>(x, stats, gsc, gbi, xnT);
  gemm_kernel<true, 128><<<dim3(8, 12, 8), dim3(256), 0, stream>>>(
      qw, xnT, qkvb, nullptr, nullptr, qT, kT, vv);
  attn_kernel<<<dim3(64, 4), dim3(256), 0, stream>>>(qT, kT, vv, aT);
  gemm_kernel<false, 64><<<dim3(16, 4, 8), dim3(256), 0, stream>>>(
      pw, aT, pjb, x, out, nullptr, nullptr, nullptr);
}

// Round 3
// 143.385 us; speedup vs baseline: 1.0418x; 1.0365x over previous
//
#include <hip/hip_runtime.h>
#include <hip/hip_bf16.h>

typedef __attribute__((ext_vector_type(8))) short v8s;            // 8 x bf16 (4 VGPRs) MFMA A/B
typedef __attribute__((ext_vector_type(8))) unsigned short u16x8;
typedef __attribute__((ext_vector_type(4))) float v4f;            // 16x16 MFMA C/D
typedef __attribute__((ext_vector_type(16))) float f32x16;        // 32x32 MFMA C/D

#define MFMA16(a, b, c) __builtin_amdgcn_mfma_f32_16x16x32_bf16((a), (b), (c), 0, 0, 0)
#define MFMA32(a, b, c) __builtin_amdgcn_mfma_f32_32x32x16_bf16((a), (b), (c), 0, 0, 0)

// async global->LDS, 16B per lane; LDS dest = wave-uniform base + lane*16
#define GLL16(g, l)                                                        \
  __builtin_amdgcn_global_load_lds(                                        \
      (const __attribute__((address_space(1))) unsigned int*)(g),          \
      (__attribute__((address_space(3))) unsigned int*)(l), 16, 0, 0)

// native v_exp_f32 (libm exp2f is a multi-op software expansion)
#if __has_builtin(__builtin_amdgcn_exp2f)
__device__ __forceinline__ float exp2n(float x) { return __builtin_amdgcn_exp2f(x); }
#else
__device__ __forceinline__ float exp2n(float x) {
  float r; asm("v_exp_f32 %0, %1" : "=v"(r) : "v"(x)); return r;
}
#endif

__device__ __forceinline__ unsigned short f2bf(float f) {
  union { float f; unsigned u; } v; v.f = f;
  unsigned r = v.u + 0x7fffu + ((v.u >> 16) & 1u);   // RNE
  return (unsigned short)(r >> 16);
}

// RNE pack of two f32 -> bf16x2 (lo in low half) in one VOP3
__device__ __forceinline__ unsigned cvtpk(float lo, float hi) {
  unsigned r;
  asm("v_cvt_pk_bf16_f32 %0, %1, %2" : "=v"(r) : "v"(lo), "v"(hi));
  return r;
}
// gfx950: swap high 32 lanes of a with low 32 lanes of b (both modified)
__device__ __forceinline__ void pl32swap(unsigned& a, unsigned& b) {
  asm("v_permlane32_swap_b32 %0, %1" : "+v"(a), "+v"(b));
}

// ---- fused: weight fp32->bf16 convert + GroupNorm (stats+normalize+transpose) ----
// blocks [0,1024): weight convert (float4 -> bf16x4 streaming)
// blocks [1024,1280): one block per (b, group): stage 16ch x 1024l slab (64KB) in LDS,
// block-reduce mu/rsigma, then normalize out of LDS and write xnT[b][l][c] bf16.
// x is read ONCE (was twice: stats pass + separate gnt kernel).
// LDS is EXACTLY 64KB (the static cap): the cross-wave reduce transits through
// slab slots 0..9 with a register save/restore (no extra LDS).
__global__ __launch_bounds__(256) void cvt_gn_kernel(const float* __restrict__ in0,
                                                     unsigned short* __restrict__ out0,
                                                     const float* __restrict__ in1,
                                                     unsigned short* __restrict__ out1,
                                                     int n0, int n1,
                                                     const float* __restrict__ x,
                                                     const float* __restrict__ gsc,
                                                     const float* __restrict__ gbi,
                                                     unsigned short* __restrict__ xnT) {
  __shared__ __align__(16) float xsf[16384];   // 64KB slab, exactly at the LDS cap
  if (blockIdx.x < 1024) {
    int i = blockIdx.x * 256 + threadIdx.x;
    const float* in; unsigned short* out;
    if (i < n0) { in = in0; out = out0; }
    else        { i -= n0; if (i >= n1) return; in = in1; out = out1; }
    float4 v = ((const float4*)in)[i];
    ushort4 o;
    o.x = f2bf(v.x); o.y = f2bf(v.y); o.z = f2bf(v.z); o.w = f2bf(v.w);
    ((ushort4*)out)[i] = o;
    return;
  }
  const int bg = blockIdx.x - 1024;            // 0..255 = b*32 + g
  const int b = bg >> 5, g = bg & 31;
  const int tid = threadIdx.x;
  const float4* xp4 = (const float4*)(x + (size_t)bg * 16384);
  float4* xs4 = (float4*)xsf;
  float s = 0.f, ss = 0.f;
  #pragma unroll
  for (int k = 0; k < 16; ++k) {
    const int i = k * 256 + tid;
    float4 v = xp4[i];
    xs4[i] = v;
    s  += (v.x + v.y) + (v.z + v.w);
    ss += (v.x * v.x + v.y * v.y) + (v.z * v.z + v.w * v.w);
  }
  #pragma unroll
  for (int d = 1; d < 64; d <<= 1) { s += __shfl_xor(s, d); ss += __shfl_xor(ss, d); }
  // cross-wave reduce through slab slots 0..9 (save/clobber/restore)
  __syncthreads();                         // slab writes visible
  float save = 0.f;
  if (tid < 10) save = xsf[tid];
  __syncthreads();                         // saves done before clobber
  if ((tid & 63) == 0) { xsf[(tid >> 6) * 2] = s; xsf[(tid >> 6) * 2 + 1] = ss; }
  __syncthreads();
  if (tid == 0) {
    const float S  = xsf[0] + xsf[2] + xsf[4] + xsf[6];
    const float SS = xsf[1] + xsf[3] + xsf[5] + xsf[7];
    const float mu  = S * (1.f / 16384.f);
    const float var = SS * (1.f / 16384.f) - mu * mu;
    xsf[8] = mu; xsf[9] = rsqrtf(var + 1e-5f);
  }
  __syncthreads();
  const float mu = xsf[8], rs = xsf[9];
  __syncthreads();                         // all reads of slots 8,9 done
  if (tid < 10) xsf[tid] = save;           // restore slab
  __syncthreads();
  float scv[16], biv[16];
  #pragma unroll
  for (int j = 0; j < 16; ++j) {
    scv[j] = gsc[g * 16 + j] * rs;
    biv[j] = gbi[g * 16 + j] - mu * scv[j];
  }
  unsigned short* dp = xnT + (size_t)b * 1024 * 512 + g * 16;
  #pragma unroll
  for (int k = 0; k < 4; ++k) {
    const int l = k * 256 + tid;
    u16x8 o0, o1;
    #pragma unroll
    for (int j = 0; j < 8; ++j) o0[j] = f2bf(xsf[j * 1024 + l] * scv[j] + biv[j]);
    #pragma unroll
    for (int j = 0; j < 8; ++j) o1[j] = f2bf(xsf[(8 + j) * 1024 + l] * scv[8 + j] + biv[8 + j]);
    *(u16x8*)(dp + (size_t)l * 512)     = o0;
    *(u16x8*)(dp + (size_t)l * 512 + 8) = o1;
  }
}

// ---------------- 128xNT MFMA GEMM, BK=64, xor-swizzled 128B LDS rows ----------------
template <bool QKV, int NT>
__global__ __launch_bounds__(256) void gemm_kernel(
    const unsigned short* __restrict__ A,
    const unsigned short* __restrict__ BT,
    const float* __restrict__ bias,
    const float* __restrict__ xres,
    float* __restrict__ outf,
    unsigned short* __restrict__ qT,
    unsigned short* __restrict__ kT,
    unsigned short* __restrict__ vO) {
  constexpr int K = 512;
  constexpr int NFR = NT / 32;              // n-frags per wave
  constexpr int NJOB = 16 + NT / 8;         // staging jobs (A:16, B:NT/8)
  const int n0 = blockIdx.x * NT, m0 = blockIdx.y * 128, b = blockIdx.z;
  const unsigned short* Bp = BT + (size_t)b * 1024 * K;

  __shared__ __align__(16) unsigned short As[128][64];
  __shared__ __align__(16) unsigned short Bs[NT][64];

  const int tid = threadIdx.x, lane = tid & 63, w = tid >> 6;
  const int quad = lane >> 4, l15 = lane & 15;
  const int wm = (w >> 1) * 64, wn = (w & 1) * (NT / 2);
  const int srow = lane >> 3;
  const int scol = ((lane & 7) ^ srow) * 8;
  const int ck0 = ((quad ^ (l15 & 7)) * 8);
  const int ck1 = ck0 ^ 32;
  const unsigned short* Asf = &As[0][0];
  const unsigned short* Bsf = &Bs[0][0];

  v4f acc[4][NFR];
  #pragma unroll
  for (int i = 0; i < 4; ++i)
    #pragma unroll
    for (int j = 0; j < NFR; ++j) acc[i][j] = (v4f){0.f, 0.f, 0.f, 0.f};

  for (int kk = 0; kk < K; kk += 64) {
    __syncthreads();
    #pragma unroll
    for (int jj = 0; jj < NJOB / 4; ++jj) {
      const int job = w * (NJOB / 4) + jj;
      if (job < 16) {
        GLL16(A + (size_t)(m0 + job * 8 + srow) * K + kk + scol, &As[job * 8][0]);
      } else {
        const int j2 = job - 16;
        GLL16(Bp + (size_t)(n0 + j2 * 8 + srow) * K + kk + scol, &Bs[j2 * 8][0]);
      }
    }
    __syncthreads();
    #pragma unroll
    for (int h = 0; h < 2; ++h) {
      const int ck = h ? ck1 : ck0;
      v8s af[4], bf[NFR];
      #pragma unroll
      for (int mt = 0; mt < 4; ++mt) af[mt] = *(const v8s*)(Asf + (wm + mt * 16 + l15) * 64 + ck);
      #pragma unroll
      for (int nt = 0; nt < NFR; ++nt) bf[nt] = *(const v8s*)(Bsf + (wn + nt * 16 + l15) * 64 + ck);
      #pragma unroll
      for (int mt = 0; mt < 4; ++mt)
        #pragma unroll
        for (int nt = 0; nt < NFR; ++nt)
          acc[mt][nt] = MFMA16(af[mt], bf[nt], acc[mt][nt]);
    }
  }

  if (QKV) {
    const int bh8 = b * 8;
    const float cs = 0.18033688011112042f;   // 0.125 * log2(e), folded into q
    #pragma unroll
    for (int mt = 0; mt < 4; ++mt) {
      const int m4 = m0 + wm + mt * 16 + quad * 4;
      const int h = m4 / 192;
      const int rr = m4 - h * 192;
      const int part = rr >> 6;                          // 0=q 1=k 2=v
      const int ch = rr & 63;
      const float b0 = bias[m4], b1 = bias[m4 + 1], b2 = bias[m4 + 2], b3 = bias[m4 + 3];
      #pragma unroll
      for (int nt = 0; nt < NFR; ++nt) {
        const int n = n0 + wn + nt * 16 + l15;
        v4f a = acc[mt][nt];
        const float v0 = a[0] + b0, v1 = a[1] + b1, v2 = a[2] + b2, v3 = a[3] + b3;
        if (part == 0) {
          ushort4 st4;
          st4.x = f2bf(v0 * cs); st4.y = f2bf(v1 * cs);
          st4.z = f2bf(v2 * cs); st4.w = f2bf(v3 * cs);
          *(ushort4*)(qT + ((size_t)(bh8 + h) * 1024 + n) * 64 + ch) = st4;
        } else if (part == 1) {
          ushort4 st4;
          st4.x = f2bf(v0); st4.y = f2bf(v1); st4.z = f2bf(v2); st4.w = f2bf(v3);
          *(ushort4*)(kT + ((size_t)(bh8 + h) * 1024 + n) * 64 + ch) = st4;
        } else {
          unsigned short* dp = vO + ((size_t)(bh8 + h) * 64 + ch) * 1024 + n;
          dp[0] = f2bf(v0); dp[1024] = f2bf(v1); dp[2048] = f2bf(v2); dp[3072] = f2bf(v3);
        }
      }
    }
  } else {
    #pragma unroll
    for (int mt = 0; mt < 4; ++mt) {
      const int m4 = m0 + wm + mt * 16 + quad * 4;
      const float b0 = bias[m4], b1 = bias[m4 + 1], b2 = bias[m4 + 2], b3 = bias[m4 + 3];
      #pragma unroll
      for (int nt = 0; nt < NFR; ++nt) {
        const int n = n0 + wn + nt * 16 + l15;
        const size_t i0 = ((size_t)b * 512 + m4) * 1024 + n;
        outf[i0]        = xres[i0]        + acc[mt][nt][0] + b0;
        outf[i0 + 1024] = xres[i0 + 1024] + acc[mt][nt][1] + b1;
        outf[i0 + 2048] = xres[i0 + 2048] + acc[mt][nt][2] + b2;
        outf[i0 + 3072] = xres[i0 + 3072] + acc[mt][nt][3] + b3;
      }
    }
  }
}

// ---------------- Flash attention: 256q/block, 64 q/wave, 128-s K/V tiles ------------
// qT/kT: [bh][1024][64] bf16 (q pre-scaled by 0.125*log2e); v: [bh][64][1024] bf16.
// grid = (bh, t): ID = bh + 64*t -> a head's t-blocks share an XCD (L2 K/V reuse).
// All MFMA on 32x32x16 bf16; S^T C-layout converted to PV A-frag with
// 8 v_cvt_pk_bf16_f32 + 4 v_permlane32_swap_b32 per 32x32 P-tile.
__global__ __launch_bounds__(256) void attn_kernel(const unsigned short* __restrict__ qT,
                                                   const unsigned short* __restrict__ kT,
                                                   const unsigned short* __restrict__ vv,
                                                   unsigned short* __restrict__ aT) {
  const int bh = blockIdx.x;
  const int t0 = blockIdx.y * 256;
  const unsigned short* qb = qT + (size_t)bh * 1024 * 64;
  const unsigned short* kb = kT + (size_t)bh * 1024 * 64;
  const unsigned short* vb = vv + (size_t)bh * 64 * 1024;

  __shared__ __align__(16) unsigned short Ks[2][128][64];    // 32KB [buf][s][k]
  __shared__ __align__(16) unsigned short Vs[2][2][64][64];  // 32KB [buf][s-half][c][s64]

  const int tid = threadIdx.x, w = tid >> 6, lane = tid & 63;
  const int l31 = lane & 31, h = lane >> 5;
  const int srow = lane >> 3;
  const int scol = ((lane & 7) ^ srow) * 8;

  // ---- stage Q (256 rows) through Ks[0..1] (exactly 256 rows), read B-frags ----
  #pragma unroll
  for (int jj = 0; jj < 8; ++jj) {
    const int seg = w * 8 + jj;              // 32 segs of 8 rows
    GLL16(qb + (size_t)(t0 + seg * 8 + srow) * 64 + scol, &Ks[0][0][0] + seg * 8 * 64);
  }
  __syncthreads();
  // Q B-frag for QK^T: B[k=ch][n=t]; lane: n = l31, k-chunk = kb2*16 + h*8
  v8s qf[2][4];
  #pragma unroll
  for (int tb = 0; tb < 2; ++tb) {
    const int row = w * 64 + tb * 32 + l31;  // row&7 == l31&7 (swizzle-consistent)
    const unsigned short* qr = &Ks[0][0][0] + row * 64;
    const int rx = row & 7;
    #pragma unroll
    for (int kb2 = 0; kb2 < 4; ++kb2)
      qf[tb][kb2] = *(const v8s*)(qr + ((kb2 * 2 + h) ^ rx) * 8);
  }
  __syncthreads();   // all waves done reading Q before Ks is overwritten

  // ---- stage K/V tile 0 (128 s): 32 jobs of 8 rows, 8 per wave ----
  #pragma unroll
  for (int jj = 0; jj < 8; ++jj) {
    const int j = w * 8 + jj;
    if (j < 16) {
      GLL16(kb + (size_t)(j * 8 + srow) * 64 + scol, &Ks[0][j * 8][0]);
    } else {
      const int j2 = j - 16, hf = j2 >> 3, cg = (j2 & 7) * 8;
      GLL16(vb + (size_t)(cg + srow) * 1024 + hf * 64 + scol, &Vs[0][hf][cg][0]);
    }
  }

  f32x16 o[2][2];
  #pragma unroll
  for (int tb = 0; tb < 2; ++tb)
    #pragma unroll
    for (int cb = 0; cb < 2; ++cb)
      #pragma unroll
      for (int r = 0; r < 16; ++r) o[tb][cb][r] = 0.f;
  float lsum[2] = {0.f, 0.f};

  for (int it = 0; it < 8; ++it) {
    __syncthreads();          // tile(it) resident (drains prefetch issued last iter)
    if (it + 1 < 8) {         // prefetch tile it+1 before compute of tile it
      const int s1 = (it + 1) * 128, bp1 = (it + 1) & 1;
      #pragma unroll
      for (int jj = 0; jj < 8; ++jj) {
        const int j = w * 8 + jj;
        if (j < 16) {
          GLL16(kb + (size_t)(s1 + j * 8 + srow) * 64 + scol, &Ks[bp1][j * 8][0]);
        } else {
          const int j2 = j - 16, hf = j2 >> 3, cg = (j2 & 7) * 8;
          GLL16(vb + (size_t)(cg + srow) * 1024 + s1 + hf * 64 + scol,
                &Vs[bp1][hf][cg][0]);
        }
      }
    }
    const int buf = it & 1;

    #pragma unroll
    for (int hf = 0; hf < 2; ++hf) {
      const unsigned short* Kb = &Ks[buf][hf * 64][0];
      const unsigned short* Vb = &Vs[buf][hf][0][0];

      // hoist K (A-frag: m = s = l31 + 32*sb) and V (B-frag: n = c = l31 + 32*cb)
      v8s kf[2][4], vf[2][4];
      #pragma unroll
      for (int sb = 0; sb < 2; ++sb) {
        const int row = sb * 32 + l31, rx = row & 7;
        const unsigned short* kr = Kb + row * 64;
        #pragma unroll
        for (int kb2 = 0; kb2 < 4; ++kb2)
          kf[sb][kb2] = *(const v8s*)(kr + ((kb2 * 2 + h) ^ rx) * 8);
      }
      #pragma unroll
      for (int cb = 0; cb < 2; ++cb) {
        const int row = cb * 32 + l31, rx = row & 7;
        const unsigned short* vr = Vb + row * 64;
        #pragma unroll
        for (int i = 0; i < 4; ++i)      // i = 16-wide s-block within this 64-s half
          vf[cb][i] = *(const v8s*)(vr + ((i * 2 + h) ^ rx) * 8);
      }

      #pragma unroll
      for (int tb = 0; tb < 2; ++tb) {
        #pragma unroll
        for (int sb = 0; sb < 2; ++sb) {
          // S^T(32s x 32t) = K * Q^T over 64 ch (4 chained k-blocks)
          f32x16 sa = {0.f,0.f,0.f,0.f,0.f,0.f,0.f,0.f,0.f,0.f,0.f,0.f,0.f,0.f,0.f,0.f};
          #pragma unroll
          for (int kb2 = 0; kb2 < 4; ++kb2)
            sa = MFMA32(kf[sb][kb2], qf[tb][kb2], sa);
          // softmax without max subtraction (q pre-scaled by log2e)
          float p[16]; float rsum = 0.f;
          #pragma unroll
          for (int r = 0; r < 16; ++r) { p[r] = exp2n(sa[r]); rsum += p[r]; }
          lsum[tb] += rsum;
          // pack P -> two 32x32x16 A-fragments (s 0..15 and 16..31)
          unsigned c0 = cvtpk(p[0], p[1]),  c1 = cvtpk(p[2], p[3]);
          unsigned c2 = cvtpk(p[4], p[5]),  c3 = cvtpk(p[6], p[7]);
          pl32swap(c0, c2); pl32swap(c1, c3);
          unsigned c4 = cvtpk(p[8], p[9]),  c5 = cvtpk(p[10], p[11]);
          unsigned c6 = cvtpk(p[12], p[13]), c7 = cvtpk(p[14], p[15]);
          pl32swap(c4, c6); pl32swap(c5, c7);
          union { v8s v; unsigned u[4]; } pa0, pa1;
          pa0.u[0] = c0; pa0.u[1] = c1; pa0.u[2] = c2; pa0.u[3] = c3;
          pa1.u[0] = c4; pa1.u[1] = c5; pa1.u[2] = c6; pa1.u[3] = c7;
          // O(32t x 64c) += P * V
          #pragma unroll
          for (int cb = 0; cb < 2; ++cb) {
            o[tb][cb] = MFMA32(pa0.v, vf[cb][sb * 2 + 0], o[tb][cb]);
            o[tb][cb] = MFMA32(pa1.v, vf[cb][sb * 2 + 1], o[tb][cb]);
          }
        }
      }
    }
  }

  // final l reduce across halves; write aT[b][t][hd*64+c] = O[t][c] / l(t)
  const int b = bh >> 3, hd = bh & 7;
  #pragma unroll
  for (int tb = 0; tb < 2; ++tb) {
    lsum[tb] += __shfl_xor(lsum[tb], 32);
    #pragma unroll
    for (int r = 0; r < 16; ++r) {
      const int trow = (r & 3) + 8 * (r >> 2) + 4 * h;
      const float inv = 1.0f / __shfl(lsum[tb], trow);
      const int t = t0 + w * 64 + tb * 32 + trow;
      unsigned short* dst = aT + ((size_t)b * 1024 + t) * 512 + hd * 64;
      dst[l31]      = f2bf(o[tb][0][r] * inv);
      dst[32 + l31] = f2bf(o[tb][1][r] * inv);
    }
  }
}

extern "C" void kernel_launch(void* const* d_in, const int* in_sizes, int n_in,
                              void* d_out, int out_size, void* d_ws, size_t ws_size,
                              hipStream_t stream) {
  const float* x    = (const float*)d_in[0];
  const float* gsc  = (const float*)d_in[1];
  const float* gbi  = (const float*)d_in[2];
  const float* qkvw = (const float*)d_in[3];
  const float* qkvb = (const float*)d_in[4];
  const float* pjw  = (const float*)d_in[5];
  const float* pjb  = (const float*)d_in[6];
  float* out = (float*)d_out;

  unsigned short* ws  = (unsigned short*)d_ws;
  unsigned short* qw  = ws;                   //  786432  qkv weights bf16
  unsigned short* pw  = qw + 786432;          //  262144  proj weights bf16
  unsigned short* xnT = pw + 262144 + 1024;   // 4194304  [b][l][c]
  unsigned short* qT  = xnT + 4194304;        // 4194304  [bh][l][64]
  unsigned short* kT  = qT + 4194304;         // 4194304  [bh][l][64]
  unsigned short* vv  = kT + 4194304;         // 4194304  [bh][64][l]
  unsigned short* aT  = vv + 4194304;         // 4194304  [b][l][c]
  // total ~44.04 MB

  cvt_gn_kernel<<<dim3(1280), dim3(256), 0, stream>>>(qkvw, qw, pjw, pw, 196608, 65536,
                                                      x, gsc, gbi, xnT);
  gemm_kernel<true, 128><<<dim3(8, 12, 8), dim3(256), 0, stream>>>(
      qw, xnT, qkvb, nullptr, nullptr, qT, kT, vv);
  attn_kernel<<<dim3(64, 4), dim3(256), 0, stream>>>(qT, kT, vv, aT);
  gemm_kernel<false, 64><<<dim3(16, 4, 8), dim3(256), 0, stream>>>(
      pw, aT, pjb, x, out, nullptr, nullptr, nullptr);
}

// Round 4
// 142.528 us; speedup vs baseline: 1.0481x; 1.0060x over previous
//
#include <hip/hip_runtime.h>
#include <hip/hip_bf16.h>

typedef __attribute__((ext_vector_type(8))) short v8s;            // 8 x bf16 (4 VGPRs) MFMA A/B
typedef __attribute__((ext_vector_type(8))) unsigned short u16x8;
typedef __attribute__((ext_vector_type(4))) float v4f;            // 16x16 MFMA C/D
typedef __attribute__((ext_vector_type(16))) float f32x16;        // 32x32 MFMA C/D

#define MFMA16(a, b, c) __builtin_amdgcn_mfma_f32_16x16x32_bf16((a), (b), (c), 0, 0, 0)
#define MFMA32(a, b, c) __builtin_amdgcn_mfma_f32_32x32x16_bf16((a), (b), (c), 0, 0, 0)

// async global->LDS, 16B per lane; LDS dest = wave-uniform base + lane*16
#define GLL16(g, l)                                                        \
  __builtin_amdgcn_global_load_lds(                                        \
      (const __attribute__((address_space(1))) unsigned int*)(g),          \
      (__attribute__((address_space(3))) unsigned int*)(l), 16, 0, 0)

// native v_exp_f32 (libm exp2f is a multi-op software expansion)
#if __has_builtin(__builtin_amdgcn_exp2f)
__device__ __forceinline__ float exp2n(float x) { return __builtin_amdgcn_exp2f(x); }
#else
__device__ __forceinline__ float exp2n(float x) {
  float r; asm("v_exp_f32 %0, %1" : "=v"(r) : "v"(x)); return r;
}
#endif

__device__ __forceinline__ unsigned short f2bf(float f) {
  union { float f; unsigned u; } v; v.f = f;
  unsigned r = v.u + 0x7fffu + ((v.u >> 16) & 1u);   // RNE
  return (unsigned short)(r >> 16);
}

// RNE pack of two f32 -> bf16x2 (lo in low half) in one VOP3
__device__ __forceinline__ unsigned cvtpk(float lo, float hi) {
  unsigned r;
  asm("v_cvt_pk_bf16_f32 %0, %1, %2" : "=v"(r) : "v"(lo), "v"(hi));
  return r;
}
// gfx950: swap high 32 lanes of a with low 32 lanes of b (both modified)
__device__ __forceinline__ void pl32swap(unsigned& a, unsigned& b) {
  asm("v_permlane32_swap_b32 %0, %1" : "+v"(a), "+v"(b));
}

// ---- fused: weight fp32->bf16 convert + GroupNorm (stats+normalize+transpose) ----
// blocks [0,1024): weight convert (float4 -> bf16x4 streaming)
// blocks [1024,1280): one block per (b, group): stage 16ch x 1024l slab (64KB) in LDS,
// block-reduce mu/rsigma, then normalize out of LDS and write xnT[b][l][c] bf16.
// x is read ONCE. LDS is EXACTLY 64KB; the cross-wave reduce transits through
// slab slots 0..9 with a register save/restore (no extra LDS).
__global__ __launch_bounds__(256) void cvt_gn_kernel(const float* __restrict__ in0,
                                                     unsigned short* __restrict__ out0,
                                                     const float* __restrict__ in1,
                                                     unsigned short* __restrict__ out1,
                                                     int n0, int n1,
                                                     const float* __restrict__ x,
                                                     const float* __restrict__ gsc,
                                                     const float* __restrict__ gbi,
                                                     unsigned short* __restrict__ xnT) {
  __shared__ __align__(16) float xsf[16384];   // 64KB slab, exactly at the LDS cap
  if (blockIdx.x < 1024) {
    int i = blockIdx.x * 256 + threadIdx.x;
    const float* in; unsigned short* out;
    if (i < n0) { in = in0; out = out0; }
    else        { i -= n0; if (i >= n1) return; in = in1; out = out1; }
    float4 v = ((const float4*)in)[i];
    ushort4 o;
    o.x = f2bf(v.x); o.y = f2bf(v.y); o.z = f2bf(v.z); o.w = f2bf(v.w);
    ((ushort4*)out)[i] = o;
    return;
  }
  const int bg = blockIdx.x - 1024;            // 0..255 = b*32 + g
  const int b = bg >> 5, g = bg & 31;
  const int tid = threadIdx.x;
  const float4* xp4 = (const float4*)(x + (size_t)bg * 16384);
  float4* xs4 = (float4*)xsf;
  float s = 0.f, ss = 0.f;
  #pragma unroll
  for (int k = 0; k < 16; ++k) {
    const int i = k * 256 + tid;
    float4 v = xp4[i];
    xs4[i] = v;
    s  += (v.x + v.y) + (v.z + v.w);
    ss += (v.x * v.x + v.y * v.y) + (v.z * v.z + v.w * v.w);
  }
  #pragma unroll
  for (int d = 1; d < 64; d <<= 1) { s += __shfl_xor(s, d); ss += __shfl_xor(ss, d); }
  // cross-wave reduce through slab slots 0..9 (save/clobber/restore)
  __syncthreads();                         // slab writes visible
  float save = 0.f;
  if (tid < 10) save = xsf[tid];
  __syncthreads();                         // saves done before clobber
  if ((tid & 63) == 0) { xsf[(tid >> 6) * 2] = s; xsf[(tid >> 6) * 2 + 1] = ss; }
  __syncthreads();
  if (tid == 0) {
    const float S  = xsf[0] + xsf[2] + xsf[4] + xsf[6];
    const float SS = xsf[1] + xsf[3] + xsf[5] + xsf[7];
    const float mu  = S * (1.f / 16384.f);
    const float var = SS * (1.f / 16384.f) - mu * mu;
    xsf[8] = mu; xsf[9] = rsqrtf(var + 1e-5f);
  }
  __syncthreads();
  const float mu = xsf[8], rs = xsf[9];
  __syncthreads();                         // all reads of slots 8,9 done
  if (tid < 10) xsf[tid] = save;           // restore slab
  __syncthreads();
  float scv[16], biv[16];
  #pragma unroll
  for (int j = 0; j < 16; ++j) {
    scv[j] = gsc[g * 16 + j] * rs;
    biv[j] = gbi[g * 16 + j] - mu * scv[j];
  }
  unsigned short* dp = xnT + (size_t)b * 1024 * 512 + g * 16;
  #pragma unroll
  for (int k = 0; k < 4; ++k) {
    const int l = k * 256 + tid;
    u16x8 o0, o1;
    #pragma unroll
    for (int j = 0; j < 8; ++j) o0[j] = f2bf(xsf[j * 1024 + l] * scv[j] + biv[j]);
    #pragma unroll
    for (int j = 0; j < 8; ++j) o1[j] = f2bf(xsf[(8 + j) * 1024 + l] * scv[8 + j] + biv[8 + j]);
    *(u16x8*)(dp + (size_t)l * 512)     = o0;
    *(u16x8*)(dp + (size_t)l * 512 + 8) = o1;
  }
}

// ---------------- 128xNT MFMA GEMM, BK=64, xor-swizzled 128B LDS rows ----------------
template <bool QKV, int NT>
__global__ __launch_bounds__(256) void gemm_kernel(
    const unsigned short* __restrict__ A,
    const unsigned short* __restrict__ BT,
    const float* __restrict__ bias,
    const float* __restrict__ xres,
    float* __restrict__ outf,
    unsigned short* __restrict__ qT,
    unsigned short* __restrict__ kT,
    unsigned short* __restrict__ vO) {
  constexpr int K = 512;
  constexpr int NFR = NT / 32;              // n-frags per wave
  constexpr int NJOB = 16 + NT / 8;         // staging jobs (A:16, B:NT/8)
  const int n0 = blockIdx.x * NT, m0 = blockIdx.y * 128, b = blockIdx.z;
  const unsigned short* Bp = BT + (size_t)b * 1024 * K;

  __shared__ __align__(16) unsigned short As[128][64];
  __shared__ __align__(16) unsigned short Bs[NT][64];

  const int tid = threadIdx.x, lane = tid & 63, w = tid >> 6;
  const int quad = lane >> 4, l15 = lane & 15;
  const int wm = (w >> 1) * 64, wn = (w & 1) * (NT / 2);
  const int srow = lane >> 3;
  const int scol = ((lane & 7) ^ srow) * 8;
  const int ck0 = ((quad ^ (l15 & 7)) * 8);
  const int ck1 = ck0 ^ 32;
  const unsigned short* Asf = &As[0][0];
  const unsigned short* Bsf = &Bs[0][0];

  v4f acc[4][NFR];
  #pragma unroll
  for (int i = 0; i < 4; ++i)
    #pragma unroll
    for (int j = 0; j < NFR; ++j) acc[i][j] = (v4f){0.f, 0.f, 0.f, 0.f};

  for (int kk = 0; kk < K; kk += 64) {
    __syncthreads();
    #pragma unroll
    for (int jj = 0; jj < NJOB / 4; ++jj) {
      const int job = w * (NJOB / 4) + jj;
      if (job < 16) {
        GLL16(A + (size_t)(m0 + job * 8 + srow) * K + kk + scol, &As[job * 8][0]);
      } else {
        const int j2 = job - 16;
        GLL16(Bp + (size_t)(n0 + j2 * 8 + srow) * K + kk + scol, &Bs[j2 * 8][0]);
      }
    }
    __syncthreads();
    #pragma unroll
    for (int h = 0; h < 2; ++h) {
      const int ck = h ? ck1 : ck0;
      v8s af[4], bf[NFR];
      #pragma unroll
      for (int mt = 0; mt < 4; ++mt) af[mt] = *(const v8s*)(Asf + (wm + mt * 16 + l15) * 64 + ck);
      #pragma unroll
      for (int nt = 0; nt < NFR; ++nt) bf[nt] = *(const v8s*)(Bsf + (wn + nt * 16 + l15) * 64 + ck);
      #pragma unroll
      for (int mt = 0; mt < 4; ++mt)
        #pragma unroll
        for (int nt = 0; nt < NFR; ++nt)
          acc[mt][nt] = MFMA16(af[mt], bf[nt], acc[mt][nt]);
    }
  }

  if (QKV) {
    const int bh8 = b * 8;
    const float cs = 0.18033688011112042f;   // 0.125 * log2(e), folded into q
    #pragma unroll
    for (int mt = 0; mt < 4; ++mt) {
      const int m4 = m0 + wm + mt * 16 + quad * 4;
      const int h = m4 / 192;
      const int rr = m4 - h * 192;
      const int part = rr >> 6;                          // 0=q 1=k 2=v
      const int ch = rr & 63;
      const float b0 = bias[m4], b1 = bias[m4 + 1], b2 = bias[m4 + 2], b3 = bias[m4 + 3];
      #pragma unroll
      for (int nt = 0; nt < NFR; ++nt) {
        const int n = n0 + wn + nt * 16 + l15;
        v4f a = acc[mt][nt];
        const float v0 = a[0] + b0, v1 = a[1] + b1, v2 = a[2] + b2, v3 = a[3] + b3;
        if (part == 0) {
          ushort4 st4;
          st4.x = f2bf(v0 * cs); st4.y = f2bf(v1 * cs);
          st4.z = f2bf(v2 * cs); st4.w = f2bf(v3 * cs);
          *(ushort4*)(qT + ((size_t)(bh8 + h) * 1024 + n) * 64 + ch) = st4;
        } else if (part == 1) {
          ushort4 st4;
          st4.x = f2bf(v0); st4.y = f2bf(v1); st4.z = f2bf(v2); st4.w = f2bf(v3);
          *(ushort4*)(kT + ((size_t)(bh8 + h) * 1024 + n) * 64 + ch) = st4;
        } else {
          unsigned short* dp = vO + ((size_t)(bh8 + h) * 64 + ch) * 1024 + n;
          dp[0] = f2bf(v0); dp[1024] = f2bf(v1); dp[2048] = f2bf(v2); dp[3072] = f2bf(v3);
        }
      }
    }
  } else {
    #pragma unroll
    for (int mt = 0; mt < 4; ++mt) {
      const int m4 = m0 + wm + mt * 16 + quad * 4;
      const float b0 = bias[m4], b1 = bias[m4 + 1], b2 = bias[m4 + 2], b3 = bias[m4 + 3];
      #pragma unroll
      for (int nt = 0; nt < NFR; ++nt) {
        const int n = n0 + wn + nt * 16 + l15;
        const size_t i0 = ((size_t)b * 512 + m4) * 1024 + n;
        outf[i0]        = xres[i0]        + acc[mt][nt][0] + b0;
        outf[i0 + 1024] = xres[i0 + 1024] + acc[mt][nt][1] + b1;
        outf[i0 + 2048] = xres[i0 + 2048] + acc[mt][nt][2] + b2;
        outf[i0 + 3072] = xres[i0 + 3072] + acc[mt][nt][3] + b3;
      }
    }
  }
}

// ---------------- Flash attention: 128q/block, 32 q/wave, 128-s K/V tiles ------------
// qT/kT: [bh][1024][64] bf16 (q pre-scaled by 0.125*log2e); v: [bh][64][1024] bf16.
// grid = (bh, t): ID = bh + 64*t -> XCD = bh%8: a head's t-blocks share an XCD L2.
// THIS ROUND: 128 q/block (was 256) -> 512 blocks = 2 blocks/CU (was 1). The attn
// counters showed the latency-bound signature (MfmaUtil 10.7, VALUBusy 18.5, Occ 10.4%
// = 1 wave/SIMD, zero TLP). 64KB LDS x2 = 128 <= 160KB, so two decoupled blocks
// co-reside and cross-hide each other's MFMA-chain / exp / ds_read / barrier stalls.
__global__ __launch_bounds__(256) void attn_kernel(const unsigned short* __restrict__ qT,
                                                   const unsigned short* __restrict__ kT,
                                                   const unsigned short* __restrict__ vv,
                                                   unsigned short* __restrict__ aT) {
  const int bh = blockIdx.x;
  const int t0 = blockIdx.y * 128;
  const unsigned short* qb = qT + (size_t)bh * 1024 * 64;
  const unsigned short* kb = kT + (size_t)bh * 1024 * 64;
  const unsigned short* vb = vv + (size_t)bh * 64 * 1024;

  __shared__ __align__(16) unsigned short Ks[2][128][64];    // 32KB [buf][s][k]
  __shared__ __align__(16) unsigned short Vs[2][2][64][64];  // 32KB [buf][s-half][c][s64]

  const int tid = threadIdx.x, w = tid >> 6, lane = tid & 63;
  const int l31 = lane & 31, h = lane >> 5;
  const int srow = lane >> 3;
  const int scol = ((lane & 7) ^ srow) * 8;

  // ---- stage Q (128 rows) through Ks[0], read B-frags ----
  #pragma unroll
  for (int jj = 0; jj < 4; ++jj) {
    const int seg = w * 4 + jj;              // 16 segs of 8 rows
    GLL16(qb + (size_t)(t0 + seg * 8 + srow) * 64 + scol, &Ks[0][0][0] + seg * 8 * 64);
  }
  __syncthreads();
  // Q B-frag for QK^T: B[k=ch][n=t]; lane: n = l31, k-chunk = kb2*16 + h*8
  v8s qf[4];
  {
    const int row = w * 32 + l31;            // row&7 == l31&7 (swizzle-consistent)
    const unsigned short* qr = &Ks[0][0][0] + row * 64;
    const int rx = row & 7;
    #pragma unroll
    for (int kb2 = 0; kb2 < 4; ++kb2)
      qf[kb2] = *(const v8s*)(qr + ((kb2 * 2 + h) ^ rx) * 8);
  }
  __syncthreads();   // all waves done reading Q before Ks is overwritten

  // ---- stage K/V tile 0 (128 s): 32 jobs of 8 rows, 8 per wave ----
  #pragma unroll
  for (int jj = 0; jj < 8; ++jj) {
    const int j = w * 8 + jj;
    if (j < 16) {
      GLL16(kb + (size_t)(j * 8 + srow) * 64 + scol, &Ks[0][j * 8][0]);
    } else {
      const int j2 = j - 16, hf = j2 >> 3, cg = (j2 & 7) * 8;
      GLL16(vb + (size_t)(cg + srow) * 1024 + hf * 64 + scol, &Vs[0][hf][cg][0]);
    }
  }

  f32x16 o[2];
  #pragma unroll
  for (int cb = 0; cb < 2; ++cb)
    #pragma unroll
    for (int r = 0; r < 16; ++r) o[cb][r] = 0.f;
  float lsum = 0.f;

  for (int it = 0; it < 8; ++it) {
    __syncthreads();          // tile(it) resident (drains prefetch issued last iter)
    if (it + 1 < 8) {         // prefetch tile it+1 before compute of tile it
      const int s1 = (it + 1) * 128, bp1 = (it + 1) & 1;
      #pragma unroll
      for (int jj = 0; jj < 8; ++jj) {
        const int j = w * 8 + jj;
        if (j < 16) {
          GLL16(kb + (size_t)(s1 + j * 8 + srow) * 64 + scol, &Ks[bp1][j * 8][0]);
        } else {
          const int j2 = j - 16, hf = j2 >> 3, cg = (j2 & 7) * 8;
          GLL16(vb + (size_t)(cg + srow) * 1024 + s1 + hf * 64 + scol,
                &Vs[bp1][hf][cg][0]);
        }
      }
    }
    const int buf = it & 1;

    #pragma unroll
    for (int hf = 0; hf < 2; ++hf) {
      const unsigned short* Kb = &Ks[buf][hf * 64][0];
      const unsigned short* Vb = &Vs[buf][hf][0][0];

      // hoist K (A-frag: m = s = l31 + 32*sb) and V (B-frag: n = c = l31 + 32*cb)
      v8s kf[2][4], vf[2][4];
      #pragma unroll
      for (int sb = 0; sb < 2; ++sb) {
        const int row = sb * 32 + l31, rx = row & 7;
        const unsigned short* kr = Kb + row * 64;
        #pragma unroll
        for (int kb2 = 0; kb2 < 4; ++kb2)
          kf[sb][kb2] = *(const v8s*)(kr + ((kb2 * 2 + h) ^ rx) * 8);
      }
      #pragma unroll
      for (int cb = 0; cb < 2; ++cb) {
        const int row = cb * 32 + l31, rx = row & 7;
        const unsigned short* vr = Vb + row * 64;
        #pragma unroll
        for (int i = 0; i < 4; ++i)      // i = 16-wide s-block within this 64-s half
          vf[cb][i] = *(const v8s*)(vr + ((i * 2 + h) ^ rx) * 8);
      }

      #pragma unroll
      for (int sb = 0; sb < 2; ++sb) {
        // S^T(32s x 32t) = K * Q^T over 64 ch (4 chained k-blocks)
        f32x16 sa = {0.f,0.f,0.f,0.f,0.f,0.f,0.f,0.f,0.f,0.f,0.f,0.f,0.f,0.f,0.f,0.f};
        #pragma unroll
        for (int kb2 = 0; kb2 < 4; ++kb2)
          sa = MFMA32(kf[sb][kb2], qf[kb2], sa);
        // softmax without max subtraction (q pre-scaled by log2e)
        float p[16]; float rsum = 0.f;
        #pragma unroll
        for (int r = 0; r < 16; ++r) { p[r] = exp2n(sa[r]); rsum += p[r]; }
        lsum += rsum;
        // pack P -> two 32x32x16 A-fragments (s 0..15 and 16..31)
        unsigned c0 = cvtpk(p[0], p[1]),  c1 = cvtpk(p[2], p[3]);
        unsigned c2 = cvtpk(p[4], p[5]),  c3 = cvtpk(p[6], p[7]);
        pl32swap(c0, c2); pl32swap(c1, c3);
        unsigned c4 = cvtpk(p[8], p[9]),  c5 = cvtpk(p[10], p[11]);
        unsigned c6 = cvtpk(p[12], p[13]), c7 = cvtpk(p[14], p[15]);
        pl32swap(c4, c6); pl32swap(c5, c7);
        union { v8s v; unsigned u[4]; } pa0, pa1;
        pa0.u[0] = c0; pa0.u[1] = c1; pa0.u[2] = c2; pa0.u[3] = c3;
        pa1.u[0] = c4; pa1.u[1] = c5; pa1.u[2] = c6; pa1.u[3] = c7;
        // O(32t x 64c) += P * V
        #pragma unroll
        for (int cb = 0; cb < 2; ++cb) {
          o[cb] = MFMA32(pa0.v, vf[cb][sb * 2 + 0], o[cb]);
          o[cb] = MFMA32(pa1.v, vf[cb][sb * 2 + 1], o[cb]);
        }
      }
    }
  }

  // final l reduce across halves; write aT[b][t][hd*64+c] = O[t][c] / l(t)
  const int b = bh >> 3, hd = bh & 7;
  lsum += __shfl_xor(lsum, 32);
  #pragma unroll
  for (int r = 0; r < 16; ++r) {
    const int trow = (r & 3) + 8 * (r >> 2) + 4 * h;
    const float inv = 1.0f / __shfl(lsum, trow);
    const int t = t0 + w * 32 + trow;
    unsigned short* dst = aT + ((size_t)b * 1024 + t) * 512 + hd * 64;
    dst[l31]      = f2bf(o[0][r] * inv);
    dst[32 + l31] = f2bf(o[1][r] * inv);
  }
}

extern "C" void kernel_launch(void* const* d_in, const int* in_sizes, int n_in,
                              void* d_out, int out_size, void* d_ws, size_t ws_size,
                              hipStream_t stream) {
  const float* x    = (const float*)d_in[0];
  const float* gsc  = (const float*)d_in[1];
  const float* gbi  = (const float*)d_in[2];
  const float* qkvw = (const float*)d_in[3];
  const float* qkvb = (const float*)d_in[4];
  const float* pjw  = (const float*)d_in[5];
  const float* pjb  = (const float*)d_in[6];
  float* out = (float*)d_out;

  unsigned short* ws  = (unsigned short*)d_ws;
  unsigned short* qw  = ws;                   //  786432  qkv weights bf16
  unsigned short* pw  = qw + 786432;          //  262144  proj weights bf16
  unsigned short* xnT = pw + 262144 + 1024;   // 4194304  [b][l][c]
  unsigned short* qT  = xnT + 4194304;        // 4194304  [bh][l][64]
  unsigned short* kT  = qT + 4194304;         // 4194304  [bh][l][64]
  unsigned short* vv  = kT + 4194304;         // 4194304  [bh][64][l]
  unsigned short* aT  = vv + 4194304;         // 4194304  [b][l][c]
  // total ~44.04 MB

  cvt_gn_kernel<<<dim3(1280), dim3(256), 0, stream>>>(qkvw, qw, pjw, pw, 196608, 65536,
                                                      x, gsc, gbi, xnT);
  gemm_kernel<true, 128><<<dim3(8, 12, 8), dim3(256), 0, stream>>>(
      qw, xnT, qkvb, nullptr, nullptr, qT, kT, vv);
  attn_kernel<<<dim3(64, 8), dim3(256), 0, stream>>>(qT, kT, vv, aT);
  gemm_kernel<false, 64><<<dim3(16, 4, 8), dim3(256), 0, stream>>>(
      pw, aT, pjb, x, out, nullptr, nullptr, nullptr);
}